// Round 1
// baseline (267.822 us; speedup 1.0000x reference)
//
#include <hip/hip_runtime.h>
#include <math.h>

#define EMBS_DIM 300
#define SCAN_BLOCK 1024

// Kernel 1: build the 300-element noise vector.
// Single block; chunked scan over samples with block-wide prefix sum of the
// acceptance mask (ballot + popcount per wave, wave totals via LDS).
__global__ __launch_bounds__(SCAN_BLOCK) void build_noise_kernel(
    const float* __restrict__ sgn, const float* __restrict__ u, int n,
    float* __restrict__ noise, float scale, float A)
{
    __shared__ int s_wave_tot[SCAN_BLOCK / 64];
    const int tid  = threadIdx.x;
    const int lane = tid & 63;
    const int wave = tid >> 6;
    const int nwaves = SCAN_BLOCK / 64;

    // Zero-init noise (d_ws is poisoned 0xAA before every launch); if fewer
    // than 300 samples are accepted the tail must be 0.
    for (int j = tid; j < EMBS_DIM; j += SCAN_BLOCK) noise[j] = 0.0f;
    __syncthreads();

    int base = 0;  // accepted-so-far; uniform across block
    for (int i0 = 0; i0 < n; i0 += SCAN_BLOCK) {
        const int i = i0 + tid;
        float r = 0.0f;
        int m = 0;
        if (i < n) {
            const float s  = sgn[i];
            const float sg = (s > 0.0f) ? 1.0f : ((s < 0.0f) ? -1.0f : 0.0f);
            r = (-scale * sg) * logf(u[i]);
            m = (r >= -A && r <= A) ? 1 : 0;
        }
        const unsigned long long bal = __ballot(m);
        if (lane == 0) s_wave_tot[wave] = __popcll(bal);
        __syncthreads();
        int woff = 0, tot = 0;
        #pragma unroll
        for (int w = 0; w < nwaves; ++w) {
            const int t = s_wave_tot[w];
            if (w < wave) woff += t;
            tot += t;
        }
        const int lpre = __popcll(bal & ((1ull << lane) - 1ull));
        const int pos  = base + woff + lpre;
        if (m && pos < EMBS_DIM) noise[pos] = r;
        base += tot;
        __syncthreads();  // protect s_wave_tot before next chunk overwrites
        if (base >= EMBS_DIM) break;
    }
}

// Kernel 2: out = embs + broadcast(noise). 300 f32 per row = 75 float4 per
// row, rows 16B-aligned (1200 B). Pure HBM-bound streaming add.
__global__ __launch_bounds__(256) void add_noise_kernel(
    const float4* __restrict__ embs, const float4* __restrict__ noise4,
    float4* __restrict__ out, int total4)
{
    const int i = blockIdx.x * 256 + threadIdx.x;
    if (i >= total4) return;
    const int j = i % (EMBS_DIM / 4);  // 75; compiler emits magic-mul
    const float4 e  = embs[i];
    const float4 nv = noise4[j];      // 1200 B resident in L1, broadcast-hot
    float4 o;
    o.x = e.x + nv.x;
    o.y = e.y + nv.y;
    o.z = e.z + nv.z;
    o.w = e.w + nv.w;
    out[i] = o;
}

extern "C" void kernel_launch(void* const* d_in, const int* in_sizes, int n_in,
                              void* d_out, int out_size, void* d_ws, size_t ws_size,
                              hipStream_t stream)
{
    const float* embs = (const float*)d_in[0];
    const float* sgn  = (const float*)d_in[1];
    const float* u    = (const float*)d_in[2];
    float* out   = (float*)d_out;
    float* noise = (float*)d_ws;      // 300 floats, 16B-aligned (alloc base)

    const int n = in_sizes[1];        // N_SAMPLES = 1,000,000

    // Match Python: _SCALE/_A computed in float64, cast to float32.
    const double scaled = 2.0 * 0.005 * sqrt(300.0) / 1.0;
    const double Ad     = -scaled * log(1.0 - 2.0 * 1.0 / sqrt(300.0));
    const float scale = (float)scaled;
    const float A     = (float)Ad;

    build_noise_kernel<<<1, SCAN_BLOCK, 0, stream>>>(sgn, u, n, noise, scale, A);

    const int total4 = out_size / 4;              // 9,830,400
    const int blocks = (total4 + 255) / 256;      // 38,400
    add_noise_kernel<<<blocks, 256, 0, stream>>>(
        (const float4*)embs, (const float4*)noise, (float4*)out, total4);
}